// Round 5
// baseline (2062.988 us; speedup 1.0000x reference)
//
#include <hip/hip_runtime.h>

typedef unsigned int u32;
typedef unsigned short u16;

#define BG 64
#define NNODE 320
#define NEDGE 1280
#define TT 256
#define FN 64
#define FG 16
#define HM 128
#define HU 128
#define HG 64
#define HA 4
#define ZM 512
#define ZU 512
#define ZG 256
#define ZA 16
#define DM 144
#define DU 208
#define DG 144
#define DA 192

// ---- conversion-area layout (floats, relative to ws+64) ----
#define CV 64
#define O_NODES 0
#define O_GA    20480
#define O_WM    21504
#define O_WHM   95232
#define O_BM    160768
#define O_WU    161280
#define O_WHU   267776
#define O_BU    333312
#define O_WG    333824
#define O_WHG   370688
#define O_BG2   387072
#define O_WA    387328
#define O_WHA   390400
#define O_BA    390464
#define CONV_TOTAL 390480
#define O_XZM   390528
#define O_XZU   (O_XZM + NEDGE * ZM)
#define O_XZG   (O_XZU + NNODE * ZU)
#define O_XZA   (O_XZG + BG * ZG)
#define O_AGGR  (O_XZA + BG * ZA)
#define O_AGGB  (O_AGGR + NNODE * HM)
#define O_UPD   (O_AGGB + BG * HU)
#define WS_FLOATS (CV + O_UPD + NNODE * HU)

__device__ __forceinline__ float bf2f(u16 v) {
  return __uint_as_float(((u32)v) << 16);
}
__device__ __forceinline__ float sigf(float x) { return 1.0f / (1.0f + __expf(-x)); }
__device__ __forceinline__ float tanh_(float x) {
  float e = __expf(-2.0f * fabsf(x));
  float t = (1.0f - e) / (1.0f + e);
  return copysignf(t, x);
}
__device__ __forceinline__ float cvt(const void* p, int i, int flag) {
  return flag ? bf2f(((const u16*)p)[i]) : ((const float*)p)[i];
}

// ---------------------------------------------------------------------------
// K-1: runtime dtype detector (on `nodes`). zlo>=50% -> fp32 storage with
// zeroed low mantissa (bf16-rounded fp32) -> fp32 path. Else bf16 iff
// exponent-byte clustering >= 50% (true bf16 ~100%, raw fp32 ~24%).
// ---------------------------------------------------------------------------
__global__ void k_detect(const u32* __restrict__ raw, int* __restrict__ flagp) {
  const int t = threadIdx.x;  // 64 threads (1 wave)
  int zlo = 0, hits = 0;
  for (int k = t; k < 256; k += 64) {
    u32 w = raw[k];
    if ((w & 0xFFFFu) == 0u) zlo++;
    u32 m = (w >> 8) & 0x7Fu;
    if (m >= 40u && m <= 70u) hits++;
  }
#pragma unroll
  for (int off = 32; off; off >>= 1) {
    zlo += __shfl_down(zlo, off, 64);
    hits += __shfl_down(hits, off, 64);
  }
  if (t == 0) *flagp = (zlo < 128 && hits >= 128) ? 1 : 0;
}

// ---------------------------------------------------------------------------
// K0: convert all weights/biases (+ t=255 slices of nodes/gattr) to fp32
// into the workspace, per the detected dtype. Biases pre-combined (bih+bhh).
// ---------------------------------------------------------------------------
__global__ __launch_bounds__(256) void k_convert(
    const void* nodes, const void* gattr,
    const void* Wm, const void* Whm, const void* bm1, const void* bm2,
    const void* Wu, const void* Whu, const void* bu1, const void* bu2,
    const void* Wg, const void* Whg, const void* bg1, const void* bg2,
    const void* Wa, const void* Wha, const void* ba1, const void* ba2,
    const int* __restrict__ flagp, float* __restrict__ dst) {
  const int flag = *flagp;
  const int i = blockIdx.x * 256 + threadIdx.x;
  if (i >= CONV_TOTAL) return;
  float v;
  if (i < O_GA) {
    int n = i >> 6, f = i & 63;
    v = cvt(nodes, (n * TT + (TT - 1)) * FN + f, flag);
  } else if (i < O_WM) {
    int l = i - O_GA; int b = l >> 4, g = l & 15;
    v = cvt(gattr, (b * TT + (TT - 1)) * FG + g, flag);
  } else if (i < O_BM) {
    v = (i < O_WHM) ? cvt(Wm, i - O_WM, flag) : cvt(Whm, i - O_WHM, flag);
  } else if (i < O_WU) {
    int l = i - O_BM; v = cvt(bm1, l, flag) + cvt(bm2, l, flag);
  } else if (i < O_BU) {
    v = (i < O_WHU) ? cvt(Wu, i - O_WU, flag) : cvt(Whu, i - O_WHU, flag);
  } else if (i < O_WG) {
    int l = i - O_BU; v = cvt(bu1, l, flag) + cvt(bu2, l, flag);
  } else if (i < O_BG2) {
    v = (i < O_WHG) ? cvt(Wg, i - O_WG, flag) : cvt(Whg, i - O_WHG, flag);
  } else if (i < O_WA) {
    int l = i - O_BG2; v = cvt(bg1, l, flag) + cvt(bg2, l, flag);
  } else if (i < O_WHA) {
    v = cvt(Wa, i - O_WA, flag);
  } else if (i < O_BA) {
    v = cvt(Wha, i - O_WHA, flag);
  } else {
    int l = i - O_BA; v = cvt(ba1, l, flag) + cvt(ba2, l, flag);
  }
  dst[i] = v;
}

// ---------------------------------------------------------------------------
// K1: parallel precompute of input projections at t = T-1 (all fp32).
// blocks [0,1280): XZm per edge; [1280,1600): XZu partial; [1600,1664): XZg
// ---------------------------------------------------------------------------
__global__ __launch_bounds__(256) void k_pre(
    const float* __restrict__ cva,
    const int* __restrict__ eidx, const int* __restrict__ num_nodes,
    const int* __restrict__ num_edges,
    float* __restrict__ XZm, float* __restrict__ XZu, float* __restrict__ XZg) {
  const int blk = blockIdx.x, tid = threadIdx.x;
  __shared__ float xv[FN];
  __shared__ float gav[FG];
  __shared__ int sgr;
  const float* nodes255 = cva + O_NODES;
  const float* ga255 = cva + O_GA;

  if (blk < NEDGE) {
    const int e = blk;
    if (tid == 0) {
      int g = 0, acc = 0;
      while (g < BG) { int c = num_edges[g]; if (e < acc + c) break; acc += c; ++g; }
      if (g >= BG) g = BG - 1;
      sgr = g;
    }
    const int srcn = eidx[e];  // faithful: src == tgt == edge_indices[0]
    if (tid < FN) xv[tid] = nodes255[srcn * FN + tid];
    __syncthreads();
    if (tid < FG) gav[tid] = ga255[sgr * FG + tid];
    __syncthreads();
    for (int j = tid; j < ZM; j += 256) {
      const float* wr = cva + O_WM + j * DM;
      float acc = cva[O_BM + j];
#pragma unroll
      for (int d = 0; d < FN; ++d) acc += (wr[d] + wr[FN + d]) * xv[d];
#pragma unroll
      for (int d = 0; d < FG; ++d) acc += wr[2 * FN + d] * gav[d];
      XZm[(size_t)e * ZM + j] = acc;
    }
  } else if (blk < NEDGE + NNODE) {
    const int n = blk - NEDGE;
    if (tid == 0) {
      int g = 0, acc = 0;
      while (g < BG) { int c = num_nodes[g]; if (n < acc + c) break; acc += c; ++g; }
      if (g >= BG) g = BG - 1;
      sgr = g;
    }
    if (tid < FN) xv[tid] = nodes255[n * FN + tid];
    __syncthreads();
    if (tid < FG) gav[tid] = ga255[sgr * FG + tid];
    __syncthreads();
    for (int j = tid; j < ZU; j += 256) {
      const float* wr = cva + O_WU + j * DU;
      float acc = cva[O_BU + j];
#pragma unroll
      for (int d = 0; d < FN; ++d) acc += wr[d] * xv[d];
#pragma unroll
      for (int d = 0; d < FG; ++d) acc += wr[FN + HM + d] * gav[d];
      XZu[(size_t)n * ZU + j] = acc;
    }
  } else {
    const int b = blk - NEDGE - NNODE;
    if (tid < FG) gav[tid] = ga255[b * FG + tid];
    __syncthreads();
    if (tid < ZG) {
      const float* wr = cva + O_WG + tid * DG;
      float acc = cva[O_BG2 + tid];
#pragma unroll
      for (int d = 0; d < FG; ++d) acc += wr[HU + d] * gav[d];
      XZg[(size_t)b * ZG + tid] = acc;
    }
  }
}

// ---------------------------------------------------------------------------
// K2: message LSTM chain, 1280 sequential steps, 1 block of 512 threads.
// Thread j owns fp32 row j of Whh_m in VGPRs. Emits relu(h) per edge into
// msgout (overlaying XZm; row e of msgout lands in already-consumed XZm
// row e/4, and within e the XZ read precedes the write across a barrier).
// ---------------------------------------------------------------------------
__global__ __launch_bounds__(512, 2) void k_msg(
    const float* __restrict__ Whh, const float* __restrict__ XZ,
    float* __restrict__ msgout) {
  const int j = threadIdx.x;
  __shared__ __align__(16) float hs[HM];
  __shared__ float zs[ZM];
  float w[HM];
  {
    const float* wr = Whh + (size_t)j * HM;
#pragma unroll
    for (int k = 0; k < HM; ++k) w[k] = wr[k];
  }
  if (j < HM) hs[j] = 0.0f;
  float c = 0.0f;
  __syncthreads();
  for (int e = 0; e < NEDGE; ++e) {
    float acc = XZ[(size_t)e * ZM + j];
    const float4* h4 = (const float4*)hs;  // same-address broadcast per wave
#pragma unroll
    for (int k = 0; k < HM / 4; ++k) {
      float4 hh = h4[k];
      acc += w[4 * k + 0] * hh.x;
      acc += w[4 * k + 1] * hh.y;
      acc += w[4 * k + 2] * hh.z;
      acc += w[4 * k + 3] * hh.w;
    }
    zs[j] = acc;
    __syncthreads();
    if (j < HM) {
      float zi = zs[j], zf = zs[HM + j], zg = zs[2 * HM + j], zo = zs[3 * HM + j];
      c = sigf(zf) * c + sigf(zi) * tanh_(zg);
      float h = sigf(zo) * tanh_(c);
      hs[j] = h;  // recurrent state is raw h; relu applies to output only
      msgout[(size_t)e * HM + j] = fmaxf(h, 0.0f);
    }
    __syncthreads();
  }
}

// ---------------------------------------------------------------------------
// K2b: generic segment_min over edges: aggr[n] = min_{e: eidx[e]==n} msg[e]
// ---------------------------------------------------------------------------
__global__ __launch_bounds__(128) void k_aggmin(
    const float* __restrict__ msg, const int* __restrict__ eidx,
    float* __restrict__ aggr) {
  const int n = blockIdx.x, j = threadIdx.x;
  float m = __uint_as_float(0x7f800000u);  // +inf (segment_min identity)
  for (int e = 0; e < NEDGE; ++e) {
    if (eidx[e] == n) m = fminf(m, msg[(size_t)e * HM + j]);
  }
  aggr[(size_t)n * HM + j] = m;
}

// ---------------------------------------------------------------------------
// K3: XZu[n] += Wih_u[:,64:192] @ aggr[n]   (parallel, 320 blocks)
// ---------------------------------------------------------------------------
__global__ __launch_bounds__(256) void k_aggproj(
    const float* __restrict__ cva, const float* __restrict__ aggr,
    float* __restrict__ XZu) {
  const int n = blockIdx.x, tid = threadIdx.x;
  __shared__ float av[HM];
  if (tid < HM) av[tid] = aggr[(size_t)n * HM + tid];
  __syncthreads();
  for (int j = tid; j < ZU; j += 256) {
    const float* wr = cva + O_WU + j * DU + FN;
    float acc = 0.0f;
#pragma unroll
    for (int k = 0; k < HM; ++k) acc += wr[k] * av[k];
    XZu[(size_t)n * ZU + j] += acc;
  }
}

// ---------------------------------------------------------------------------
// K4: node-update LSTM chain, 320 steps, 1 block of 512 threads.
// ---------------------------------------------------------------------------
__global__ __launch_bounds__(512, 2) void k_upd(
    const float* __restrict__ Whh, const float* __restrict__ XZ,
    float* __restrict__ upd) {
  const int j = threadIdx.x;
  __shared__ __align__(16) float hs[HU];
  __shared__ float zs[ZU];
  float w[HU];
  {
    const float* wr = Whh + (size_t)j * HU;
#pragma unroll
    for (int k = 0; k < HU; ++k) w[k] = wr[k];
  }
  if (j < HU) hs[j] = 0.0f;
  float c = 0.0f;
  __syncthreads();
  for (int n = 0; n < NNODE; ++n) {
    float acc = XZ[(size_t)n * ZU + j];
    const float4* h4 = (const float4*)hs;
#pragma unroll
    for (int k = 0; k < HU / 4; ++k) {
      float4 hh = h4[k];
      acc += w[4 * k + 0] * hh.x;
      acc += w[4 * k + 1] * hh.y;
      acc += w[4 * k + 2] * hh.z;
      acc += w[4 * k + 3] * hh.w;
    }
    zs[j] = acc;
    __syncthreads();
    if (j < HU) {
      float zi = zs[j], zf = zs[HU + j], zg = zs[2 * HU + j], zo = zs[3 * HU + j];
      c = sigf(zf) * c + sigf(zi) * tanh_(zg);
      float h = sigf(zo) * tanh_(c);
      hs[j] = h;
      upd[(size_t)n * HU + j] = fmaxf(h, 0.0f);
    }
    __syncthreads();
  }
}

// ---------------------------------------------------------------------------
// K4b: generic segment_min over nodes: aggB[b] = min_{n: bidx[n]==b} upd[n]
// ---------------------------------------------------------------------------
__global__ __launch_bounds__(128) void k_aggbmin(
    const float* __restrict__ upd, const int* __restrict__ bidx,
    float* __restrict__ aggB) {
  const int b = blockIdx.x, j = threadIdx.x;
  float m = __uint_as_float(0x7f800000u);
  for (int n = 0; n < NNODE; ++n) {
    if (bidx[n] == b) m = fminf(m, upd[(size_t)n * HU + j]);
  }
  aggB[(size_t)b * HU + j] = m;
}

// ---------------------------------------------------------------------------
// K5: blocks [0,64): XZg[b] += Wih_g[:,0:128] @ aggB[b]
//     blocks [64,128): XZa[b] = Wih_a[:,0:128] @ chosen[b] + biases
// ---------------------------------------------------------------------------
__global__ __launch_bounds__(256) void k_gproj(
    const float* __restrict__ cva,
    const float* __restrict__ aggB, const float* __restrict__ upd,
    const int* __restrict__ bidx, const int* __restrict__ who,
    float* __restrict__ XZg, float* __restrict__ XZa) {
  const int blk = blockIdx.x, tid = threadIdx.x;
  __shared__ float buf[HU];
  __shared__ int satbw;
  if (blk < BG) {
    const int b = blk;
    if (tid < HU) buf[tid] = aggB[(size_t)b * HU + tid];
    __syncthreads();
    if (tid < ZG) {
      const float* wr = cva + O_WG + tid * DG;
      float acc = 0.0f;
#pragma unroll
      for (int k = 0; k < HU; ++k) acc += wr[k] * buf[k];
      XZg[(size_t)b * ZG + tid] += acc;
    }
  } else {
    const int b = blk - BG;
    const int whoB = who[b];
    if (tid == 0) {
      int off = 0;
      for (int i = 0; i < NNODE; ++i) off += (bidx[i] < b) ? 1 : 0;
      const int adj = (whoB == 3) ? 2 : whoB;
      satbw = (b == 0) ? who[0] : (adj + off);
    }
    __syncthreads();
    if (tid < HU) {
      float v;
      if (whoB == 3) v = aggB[(size_t)b * HU + tid];
      else v = upd[(size_t)satbw * HU + tid];
      buf[tid] = v;
    }
    __syncthreads();
    if (tid < ZA) {
      const float* wr = cva + O_WA + tid * DA;
      float acc = cva[O_BA + tid];
#pragma unroll
      for (int k = 0; k < HU; ++k) acc += wr[k] * buf[k];
      XZa[(size_t)b * ZA + tid] = acc;
    }
  }
}

// ---------------------------------------------------------------------------
// K6: group LSTM chain (64 steps, H=64) + action LSTM chain (64 steps, H=4)
//     + softmax + FP32 output (reference returns float32).
// ---------------------------------------------------------------------------
__global__ __launch_bounds__(256, 2) void k_final(
    const float* __restrict__ cva, const float* __restrict__ XZg,
    const float* __restrict__ XZa, float* __restrict__ out) {
  const int j = threadIdx.x;
  __shared__ __align__(16) float hg[HG];
  __shared__ float zsg[ZG];
  __shared__ float grp[BG * HG];
  __shared__ float za[ZA];
  __shared__ float haL[HA];
  __shared__ float res[BG * HA];

  float wg[HG];
  {
    const float* wr = cva + O_WHG + j * HG;
#pragma unroll
    for (int k = 0; k < HG; ++k) wg[k] = wr[k];
  }
  if (j < HG) hg[j] = 0.0f;
  float cg = 0.0f;
  __syncthreads();
  for (int b = 0; b < BG; ++b) {
    float acc = XZg[(size_t)b * ZG + j];
#pragma unroll
    for (int k = 0; k < HG; ++k) acc += wg[k] * hg[k];
    zsg[j] = acc;
    __syncthreads();
    if (j < HG) {
      float zi = zsg[j], zf = zsg[HG + j], zg = zsg[2 * HG + j], zo = zsg[3 * HG + j];
      cg = sigf(zf) * cg + sigf(zi) * tanh_(zg);
      float h = sigf(zo) * tanh_(cg);
      hg[j] = h;
      grp[b * HG + j] = fmaxf(h, 0.0f);
    }
    __syncthreads();
  }

  // action chain
  float wa2[HG];
  float wha[HA];
  if (j < ZA) {
    const float* wr2 = cva + O_WA + j * DA + HU;
#pragma unroll
    for (int k = 0; k < HG; ++k) wa2[k] = wr2[k];
#pragma unroll
    for (int k = 0; k < HA; ++k) wha[k] = cva[O_WHA + j * HA + k];
  }
  if (j < HA) haL[j] = 0.0f;
  float ca = 0.0f;
  __syncthreads();
  for (int b = 0; b < BG; ++b) {
    if (j < ZA) {
      float acc = XZa[(size_t)b * ZA + j];
#pragma unroll
      for (int k = 0; k < HG; ++k) acc += wa2[k] * grp[b * HG + k];
#pragma unroll
      for (int k = 0; k < HA; ++k) acc += wha[k] * haL[k];
      za[j] = acc;
    }
    __syncthreads();
    if (j < HA) {
      float zi = za[j], zf = za[HA + j], zg = za[2 * HA + j], zo = za[3 * HA + j];
      ca = sigf(zf) * ca + sigf(zi) * tanh_(zg);
      float h = sigf(zo) * tanh_(ca);
      haL[j] = h;
      res[b * HA + j] = h;
    }
    __syncthreads();
  }
  // softmax over the 4 actions per graph, write fp32
  if (j < BG) {
    float x0 = res[j * 4 + 0], x1 = res[j * 4 + 1];
    float x2 = res[j * 4 + 2], x3 = res[j * 4 + 3];
    float m = fmaxf(fmaxf(x0, x1), fmaxf(x2, x3));
    float e0 = __expf(x0 - m), e1 = __expf(x1 - m);
    float e2 = __expf(x2 - m), e3 = __expf(x3 - m);
    float s = e0 + e1 + e2 + e3;
    out[j * 4 + 0] = e0 / s;
    out[j * 4 + 1] = e1 / s;
    out[j * 4 + 2] = e2 / s;
    out[j * 4 + 3] = e3 / s;
  }
}

// fallback: ws too small -> write zeros (finite signal, distinguishes theories)
__global__ void k_zero(float* out) { out[threadIdx.x] = 0.0f; }

extern "C" void kernel_launch(void* const* d_in, const int* in_sizes, int n_in,
                              void* d_out, int out_size, void* d_ws, size_t ws_size,
                              hipStream_t stream) {
  const void* nodes = d_in[0];
  const void* gattr = d_in[1];
  const int* eidx  = (const int*)d_in[2];
  const int* nn    = (const int*)d_in[3];
  const int* ne    = (const int*)d_in[4];
  const int* bidx  = (const int*)d_in[5];
  const int* who   = (const int*)d_in[6];

  if (ws_size < (size_t)WS_FLOATS * 4) {
    k_zero<<<1, 256, 0, stream>>>((float*)d_out);
    return;
  }

  float* ws = (float*)d_ws;
  int* flagp = (int*)d_ws;
  float* cva = ws + CV;
  float* XZm = cva + O_XZM;
  float* XZu = cva + O_XZU;
  float* XZg = cva + O_XZG;
  float* XZa = cva + O_XZA;
  float* aggr = cva + O_AGGR;
  float* aggB = cva + O_AGGB;
  float* upd = cva + O_UPD;
  float* msg = XZm;  // overlay (safe: see k_msg comment)

  k_detect<<<1, 64, 0, stream>>>((const u32*)nodes, flagp);
  k_convert<<<(CONV_TOTAL + 255) / 256, 256, 0, stream>>>(
      nodes, gattr,
      d_in[7], d_in[8], d_in[9], d_in[10],
      d_in[11], d_in[12], d_in[13], d_in[14],
      d_in[15], d_in[16], d_in[17], d_in[18],
      d_in[19], d_in[20], d_in[21], d_in[22],
      flagp, cva);
  k_pre<<<NEDGE + NNODE + BG, 256, 0, stream>>>(cva, eidx, nn, ne, XZm, XZu, XZg);
  k_msg<<<1, 512, 0, stream>>>(cva + O_WHM, XZm, msg);
  k_aggmin<<<NNODE, 128, 0, stream>>>(msg, eidx, aggr);
  k_aggproj<<<NNODE, 256, 0, stream>>>(cva, aggr, XZu);
  k_upd<<<1, 512, 0, stream>>>(cva + O_WHU, XZu, upd);
  k_aggbmin<<<BG, 128, 0, stream>>>(upd, bidx, aggB);
  k_gproj<<<2 * BG, 256, 0, stream>>>(cva, aggB, upd, bidx, who, XZg, XZa);
  k_final<<<1, 256, 0, stream>>>(cva, XZg, XZa, (float*)d_out);
}

// Round 6
// 1810.600 us; speedup vs baseline: 1.1394x; 1.1394x over previous
//
#include <hip/hip_runtime.h>

typedef unsigned int u32;
typedef unsigned short u16;

#define BG 64
#define NNODE 320
#define NEDGE 1280
#define TT 256
#define FN 64
#define FG 16
#define HM 128
#define HU 128
#define HG 64
#define HA 4
#define ZM 512
#define ZU 512
#define ZG 256
#define ZA 16
#define DM 144
#define DU 208
#define DG 144
#define DA 192

// ---- conversion-area layout (floats, relative to ws+64) ----
#define CV 64
#define O_NODES 0
#define O_GA    20480
#define O_WM    21504
#define O_WHM   95232
#define O_BM    160768
#define O_WU    161280
#define O_WHU   267776
#define O_BU    333312
#define O_WG    333824
#define O_WHG   370688
#define O_BG2   387072
#define O_WA    387328
#define O_WHA   390400
#define O_BA    390464
#define CONV_TOTAL 390480
#define O_XZM   390528
#define O_XZU   (O_XZM + NEDGE * ZM)
#define O_XZG   (O_XZU + NNODE * ZU)
#define O_XZA   (O_XZG + BG * ZG)
#define O_AGGR  (O_XZA + BG * ZA)
#define O_AGGB  (O_AGGR + NNODE * HM)
#define O_UPD   (O_AGGB + BG * HU)
#define WS_FLOATS (CV + O_UPD + NNODE * HU)

__device__ __forceinline__ float bf2f(u16 v) {
  return __uint_as_float(((u32)v) << 16);
}
__device__ __forceinline__ float sigf(float x) { return 1.0f / (1.0f + __expf(-x)); }
__device__ __forceinline__ float tanh_(float x) {
  float e = __expf(-2.0f * fabsf(x));
  float t = (1.0f - e) / (1.0f + e);
  return copysignf(t, x);
}
__device__ __forceinline__ float cvt(const void* p, int i, int flag) {
  return flag ? bf2f(((const u16*)p)[i]) : ((const float*)p)[i];
}

// lgkmcnt-only barrier: LDS ordering without the vmcnt(0) drain that
// __syncthreads() emits. Global ops here are fire-and-forget stores (consumed
// by later kernels; visible at dispatch end) and prefetch loads (compiler
// inserts vmcnt wait at first use). See k_chain ordering proof in comments.
#define BAR() asm volatile("s_waitcnt lgkmcnt(0)\n\ts_barrier" ::: "memory")

// ---------------------------------------------------------------------------
// K-1: runtime dtype detector (unchanged from round 5; fp32 was detected).
// ---------------------------------------------------------------------------
__global__ void k_detect(const u32* __restrict__ raw, int* __restrict__ flagp) {
  const int t = threadIdx.x;  // 64 threads (1 wave)
  int zlo = 0, hits = 0;
  for (int k = t; k < 256; k += 64) {
    u32 w = raw[k];
    if ((w & 0xFFFFu) == 0u) zlo++;
    u32 m = (w >> 8) & 0x7Fu;
    if (m >= 40u && m <= 70u) hits++;
  }
#pragma unroll
  for (int off = 32; off; off >>= 1) {
    zlo += __shfl_down(zlo, off, 64);
    hits += __shfl_down(hits, off, 64);
  }
  if (t == 0) *flagp = (zlo < 128 && hits >= 128) ? 1 : 0;
}

// ---------------------------------------------------------------------------
// K0: convert weights/biases (+ t=255 slices) to fp32 in workspace.
// ---------------------------------------------------------------------------
__global__ __launch_bounds__(256) void k_convert(
    const void* nodes, const void* gattr,
    const void* Wm, const void* Whm, const void* bm1, const void* bm2,
    const void* Wu, const void* Whu, const void* bu1, const void* bu2,
    const void* Wg, const void* Whg, const void* bg1, const void* bg2,
    const void* Wa, const void* Wha, const void* ba1, const void* ba2,
    const int* __restrict__ flagp, float* __restrict__ dst) {
  const int flag = *flagp;
  const int i = blockIdx.x * 256 + threadIdx.x;
  if (i >= CONV_TOTAL) return;
  float v;
  if (i < O_GA) {
    int n = i >> 6, f = i & 63;
    v = cvt(nodes, (n * TT + (TT - 1)) * FN + f, flag);
  } else if (i < O_WM) {
    int l = i - O_GA; int b = l >> 4, g = l & 15;
    v = cvt(gattr, (b * TT + (TT - 1)) * FG + g, flag);
  } else if (i < O_BM) {
    v = (i < O_WHM) ? cvt(Wm, i - O_WM, flag) : cvt(Whm, i - O_WHM, flag);
  } else if (i < O_WU) {
    int l = i - O_BM; v = cvt(bm1, l, flag) + cvt(bm2, l, flag);
  } else if (i < O_BU) {
    v = (i < O_WHU) ? cvt(Wu, i - O_WU, flag) : cvt(Whu, i - O_WHU, flag);
  } else if (i < O_WG) {
    int l = i - O_BU; v = cvt(bu1, l, flag) + cvt(bu2, l, flag);
  } else if (i < O_BG2) {
    v = (i < O_WHG) ? cvt(Wg, i - O_WG, flag) : cvt(Whg, i - O_WHG, flag);
  } else if (i < O_WA) {
    int l = i - O_BG2; v = cvt(bg1, l, flag) + cvt(bg2, l, flag);
  } else if (i < O_WHA) {
    v = cvt(Wa, i - O_WA, flag);
  } else if (i < O_BA) {
    v = cvt(Wha, i - O_WHA, flag);
  } else {
    int l = i - O_BA; v = cvt(ba1, l, flag) + cvt(ba2, l, flag);
  }
  dst[i] = v;
}

// ---------------------------------------------------------------------------
// K1: parallel precompute of input projections at t = T-1 (unchanged).
// ---------------------------------------------------------------------------
__global__ __launch_bounds__(256) void k_pre(
    const float* __restrict__ cva,
    const int* __restrict__ eidx, const int* __restrict__ num_nodes,
    const int* __restrict__ num_edges,
    float* __restrict__ XZm, float* __restrict__ XZu, float* __restrict__ XZg) {
  const int blk = blockIdx.x, tid = threadIdx.x;
  __shared__ float xv[FN];
  __shared__ float gav[FG];
  __shared__ int sgr;
  const float* nodes255 = cva + O_NODES;
  const float* ga255 = cva + O_GA;

  if (blk < NEDGE) {
    const int e = blk;
    if (tid == 0) {
      int g = 0, acc = 0;
      while (g < BG) { int c = num_edges[g]; if (e < acc + c) break; acc += c; ++g; }
      if (g >= BG) g = BG - 1;
      sgr = g;
    }
    const int srcn = eidx[e];  // faithful: src == tgt == edge_indices[0]
    if (tid < FN) xv[tid] = nodes255[srcn * FN + tid];
    __syncthreads();
    if (tid < FG) gav[tid] = ga255[sgr * FG + tid];
    __syncthreads();
    for (int j = tid; j < ZM; j += 256) {
      const float* wr = cva + O_WM + j * DM;
      float acc = cva[O_BM + j];
#pragma unroll
      for (int d = 0; d < FN; ++d) acc += (wr[d] + wr[FN + d]) * xv[d];
#pragma unroll
      for (int d = 0; d < FG; ++d) acc += wr[2 * FN + d] * gav[d];
      XZm[(size_t)e * ZM + j] = acc;
    }
  } else if (blk < NEDGE + NNODE) {
    const int n = blk - NEDGE;
    if (tid == 0) {
      int g = 0, acc = 0;
      while (g < BG) { int c = num_nodes[g]; if (n < acc + c) break; acc += c; ++g; }
      if (g >= BG) g = BG - 1;
      sgr = g;
    }
    if (tid < FN) xv[tid] = nodes255[n * FN + tid];
    __syncthreads();
    if (tid < FG) gav[tid] = ga255[sgr * FG + tid];
    __syncthreads();
    for (int j = tid; j < ZU; j += 256) {
      const float* wr = cva + O_WU + j * DU;
      float acc = cva[O_BU + j];
#pragma unroll
      for (int d = 0; d < FN; ++d) acc += wr[d] * xv[d];
#pragma unroll
      for (int d = 0; d < FG; ++d) acc += wr[FN + HM + d] * gav[d];
      XZu[(size_t)n * ZU + j] = acc;
    }
  } else {
    const int b = blk - NEDGE - NNODE;
    if (tid < FG) gav[tid] = ga255[b * FG + tid];
    __syncthreads();
    if (tid < ZG) {
      const float* wr = cva + O_WG + tid * DG;
      float acc = cva[O_BG2 + tid];
#pragma unroll
      for (int d = 0; d < FG; ++d) acc += wr[HU + d] * gav[d];
      XZg[(size_t)b * ZG + tid] = acc;
    }
  }
}

// ---------------------------------------------------------------------------
// K2/K4: LSTM chain, lane-parallel-k formulation. 512 threads, 1 block.
// Group = 4 lanes (kc = lane&3 -> k-chunk of 32). Group g of wave w owns
// element e = w*16+g; pass p in [0,4) computes row p*128+e = gate p of e.
// All 4 gate z's end in-register in every lane of the group (replicated);
// gates computed by all lanes -> no z LDS round trip, no idle waves.
// h double-buffered in LDS (padded: 4 chunks x 36 floats, conflict-free
// b128 reads) -> ONE lgkmcnt-only barrier per step.
// Ordering proof for overlay (k_msg: hout overlays XZ region):
//   store of step e-1's h at step e touches XZ floats [(e-1)*128,(e)*128)
//   i.e. XZ row (e-1)/4 <= e-1; every wave consumed that row's loads
//   (vmcnt-waited at its z compute) before passing barrier e-1; prefetch at
//   step e reads row e+1 > (e-1)/4. No in-flight load can see the store.
// ---------------------------------------------------------------------------
template <int STEPS>
__global__ __launch_bounds__(512, 2) void k_chain(
    const float* __restrict__ Whh, const float* __restrict__ XZ,
    float* __restrict__ hout) {
  const int lane = threadIdx.x & 63;
  const int wv = threadIdx.x >> 6;  // wave 0..7
  const int kc = lane & 3;          // k-chunk 0..3 (32 floats each)
  const int g = lane >> 2;          // group 0..15
  const int elem = wv * 16 + g;     // element 0..127
  __shared__ float hbuf[2][144];    // 4 chunks x 36 (4-float pad)

  float wreg[128];  // Whh rows {p*128+elem}, cols kc*32..+31
#pragma unroll
  for (int p = 0; p < 4; ++p) {
    const float* wr = Whh + (size_t)(p * 128 + elem) * 128 + kc * 32;
#pragma unroll
    for (int k = 0; k < 32; ++k) wreg[p * 32 + k] = wr[k];
  }
  if (threadIdx.x < 144) hbuf[0][threadIdx.x] = 0.0f;
  float c = 0.0f;
  float hrelu_prev = 0.0f;
  float xz[4];
#pragma unroll
  for (int p = 0; p < 4; ++p) xz[p] = XZ[p * 128 + elem];
  BAR();
  int cur = 0;
  for (int e = 0; e < STEPS; ++e) {
    // h chunk (32 floats) from LDS, conflict-free b128
    float hv[32];
    const float4* hb = (const float4*)&hbuf[cur][kc * 36];
#pragma unroll
    for (int q = 0; q < 8; ++q) {
      float4 t = hb[q];
      hv[q * 4 + 0] = t.x; hv[q * 4 + 1] = t.y;
      hv[q * 4 + 2] = t.z; hv[q * 4 + 3] = t.w;
    }
    float z[4];
#pragma unroll
    for (int p = 0; p < 4; ++p) {
      float a0 = 0.0f, a1 = 0.0f;
#pragma unroll
      for (int k = 0; k < 16; ++k) {
        a0 += wreg[p * 32 + k] * hv[k];
        a1 += wreg[p * 32 + 16 + k] * hv[16 + k];
      }
      float s = a0 + a1;
      s += __shfl_xor(s, 1, 64);
      s += __shfl_xor(s, 2, 64);
      z[p] = xz[p] + s;
    }
    // prefetch next step's XZ (no barrier dependency; vmcnt at next use)
    if (e + 1 < STEPS) {
      const float* xp = XZ + (size_t)(e + 1) * 512;
#pragma unroll
      for (int p = 0; p < 4; ++p) xz[p] = xp[p * 128 + elem];
    }
    // gates: z[0]=i, z[1]=f, z[2]=g, z[3]=o (replicated across group)
    c = sigf(z[1]) * c + sigf(z[0]) * tanh_(z[2]);
    float h = sigf(z[3]) * tanh_(c);
    if (kc == 0) {
      hbuf[cur ^ 1][(elem >> 5) * 36 + (elem & 31)] = h;
      if (e > 0) hout[(size_t)(e - 1) * 128 + elem] = hrelu_prev;
      hrelu_prev = fmaxf(h, 0.0f);
    }
    BAR();
    cur ^= 1;
  }
  if (kc == 0) hout[(size_t)(STEPS - 1) * 128 + elem] = hrelu_prev;
}

// ---------------------------------------------------------------------------
// K2b: generic segment_min over edges: aggr[n] = min_{e: eidx[e]==n} msg[e]
// ---------------------------------------------------------------------------
__global__ __launch_bounds__(128) void k_aggmin(
    const float* __restrict__ msg, const int* __restrict__ eidx,
    float* __restrict__ aggr) {
  const int n = blockIdx.x, j = threadIdx.x;
  float m = __uint_as_float(0x7f800000u);  // +inf (segment_min identity)
  for (int e = 0; e < NEDGE; ++e) {
    if (eidx[e] == n) m = fminf(m, msg[(size_t)e * HM + j]);
  }
  aggr[(size_t)n * HM + j] = m;
}

// ---------------------------------------------------------------------------
// K3: XZu[n] += Wih_u[:,64:192] @ aggr[n]   (parallel, 320 blocks)
// ---------------------------------------------------------------------------
__global__ __launch_bounds__(256) void k_aggproj(
    const float* __restrict__ cva, const float* __restrict__ aggr,
    float* __restrict__ XZu) {
  const int n = blockIdx.x, tid = threadIdx.x;
  __shared__ float av[HM];
  if (tid < HM) av[tid] = aggr[(size_t)n * HM + tid];
  __syncthreads();
  for (int j = tid; j < ZU; j += 256) {
    const float* wr = cva + O_WU + j * DU + FN;
    float acc = 0.0f;
#pragma unroll
    for (int k = 0; k < HM; ++k) acc += wr[k] * av[k];
    XZu[(size_t)n * ZU + j] += acc;
  }
}

// ---------------------------------------------------------------------------
// K4b: generic segment_min over nodes: aggB[b] = min_{n: bidx[n]==b} upd[n]
// ---------------------------------------------------------------------------
__global__ __launch_bounds__(128) void k_aggbmin(
    const float* __restrict__ upd, const int* __restrict__ bidx,
    float* __restrict__ aggB) {
  const int b = blockIdx.x, j = threadIdx.x;
  float m = __uint_as_float(0x7f800000u);
  for (int n = 0; n < NNODE; ++n) {
    if (bidx[n] == b) m = fminf(m, upd[(size_t)n * HU + j]);
  }
  aggB[(size_t)b * HU + j] = m;
}

// ---------------------------------------------------------------------------
// K5: blocks [0,64): XZg[b] += Wih_g[:,0:128] @ aggB[b]
//     blocks [64,128): XZa[b] = Wih_a[:,0:128] @ chosen[b] + biases
// ---------------------------------------------------------------------------
__global__ __launch_bounds__(256) void k_gproj(
    const float* __restrict__ cva,
    const float* __restrict__ aggB, const float* __restrict__ upd,
    const int* __restrict__ bidx, const int* __restrict__ who,
    float* __restrict__ XZg, float* __restrict__ XZa) {
  const int blk = blockIdx.x, tid = threadIdx.x;
  __shared__ float buf[HU];
  __shared__ int satbw;
  if (blk < BG) {
    const int b = blk;
    if (tid < HU) buf[tid] = aggB[(size_t)b * HU + tid];
    __syncthreads();
    if (tid < ZG) {
      const float* wr = cva + O_WG + tid * DG;
      float acc = 0.0f;
#pragma unroll
      for (int k = 0; k < HU; ++k) acc += wr[k] * buf[k];
      XZg[(size_t)b * ZG + tid] += acc;
    }
  } else {
    const int b = blk - BG;
    const int whoB = who[b];
    if (tid == 0) {
      int off = 0;
      for (int i = 0; i < NNODE; ++i) off += (bidx[i] < b) ? 1 : 0;
      const int adj = (whoB == 3) ? 2 : whoB;
      satbw = (b == 0) ? who[0] : (adj + off);
    }
    __syncthreads();
    if (tid < HU) {
      float v;
      if (whoB == 3) v = aggB[(size_t)b * HU + tid];
      else v = upd[(size_t)satbw * HU + tid];
      buf[tid] = v;
    }
    __syncthreads();
    if (tid < ZA) {
      const float* wr = cva + O_WA + tid * DA;
      float acc = cva[O_BA + tid];
#pragma unroll
      for (int k = 0; k < HU; ++k) acc += wr[k] * buf[k];
      XZa[(size_t)b * ZA + tid] = acc;
    }
  }
}

// ---------------------------------------------------------------------------
// K6: group LSTM chain (64 steps, H=64) + action chain + softmax + fp32 out.
// ---------------------------------------------------------------------------
__global__ __launch_bounds__(256, 2) void k_final(
    const float* __restrict__ cva, const float* __restrict__ XZg,
    const float* __restrict__ XZa, float* __restrict__ out) {
  const int j = threadIdx.x;
  __shared__ __align__(16) float hg[HG];
  __shared__ float zsg[ZG];
  __shared__ float grp[BG * HG];
  __shared__ float za[ZA];
  __shared__ float haL[HA];
  __shared__ float res[BG * HA];

  float wg[HG];
  {
    const float* wr = cva + O_WHG + j * HG;
#pragma unroll
    for (int k = 0; k < HG; ++k) wg[k] = wr[k];
  }
  if (j < HG) hg[j] = 0.0f;
  float cg = 0.0f;
  __syncthreads();
  for (int b = 0; b < BG; ++b) {
    float acc = XZg[(size_t)b * ZG + j];
#pragma unroll
    for (int k = 0; k < HG; ++k) acc += wg[k] * hg[k];
    zsg[j] = acc;
    __syncthreads();
    if (j < HG) {
      float zi = zsg[j], zf = zsg[HG + j], zg = zsg[2 * HG + j], zo = zsg[3 * HG + j];
      cg = sigf(zf) * cg + sigf(zi) * tanh_(zg);
      float h = sigf(zo) * tanh_(cg);
      hg[j] = h;
      grp[b * HG + j] = fmaxf(h, 0.0f);
    }
    __syncthreads();
  }

  float wa2[HG];
  float wha[HA];
  if (j < ZA) {
    const float* wr2 = cva + O_WA + j * DA + HU;
#pragma unroll
    for (int k = 0; k < HG; ++k) wa2[k] = wr2[k];
#pragma unroll
    for (int k = 0; k < HA; ++k) wha[k] = cva[O_WHA + j * HA + k];
  }
  if (j < HA) haL[j] = 0.0f;
  float ca = 0.0f;
  __syncthreads();
  for (int b = 0; b < BG; ++b) {
    if (j < ZA) {
      float acc = XZa[(size_t)b * ZA + j];
#pragma unroll
      for (int k = 0; k < HG; ++k) acc += wa2[k] * grp[b * HG + k];
#pragma unroll
      for (int k = 0; k < HA; ++k) acc += wha[k] * haL[k];
      za[j] = acc;
    }
    __syncthreads();
    if (j < HA) {
      float zi = za[j], zf = za[HA + j], zg = za[2 * HA + j], zo = za[3 * HA + j];
      ca = sigf(zf) * ca + sigf(zi) * tanh_(zg);
      float h = sigf(zo) * tanh_(ca);
      haL[j] = h;
      res[b * HA + j] = h;
    }
    __syncthreads();
  }
  if (j < BG) {
    float x0 = res[j * 4 + 0], x1 = res[j * 4 + 1];
    float x2 = res[j * 4 + 2], x3 = res[j * 4 + 3];
    float m = fmaxf(fmaxf(x0, x1), fmaxf(x2, x3));
    float e0 = __expf(x0 - m), e1 = __expf(x1 - m);
    float e2 = __expf(x2 - m), e3 = __expf(x3 - m);
    float s = e0 + e1 + e2 + e3;
    out[j * 4 + 0] = e0 / s;
    out[j * 4 + 1] = e1 / s;
    out[j * 4 + 2] = e2 / s;
    out[j * 4 + 3] = e3 / s;
  }
}

__global__ void k_zero(float* out) { out[threadIdx.x] = 0.0f; }

extern "C" void kernel_launch(void* const* d_in, const int* in_sizes, int n_in,
                              void* d_out, int out_size, void* d_ws, size_t ws_size,
                              hipStream_t stream) {
  const void* nodes = d_in[0];
  const void* gattr = d_in[1];
  const int* eidx  = (const int*)d_in[2];
  const int* nn    = (const int*)d_in[3];
  const int* ne    = (const int*)d_in[4];
  const int* bidx  = (const int*)d_in[5];
  const int* who   = (const int*)d_in[6];

  if (ws_size < (size_t)WS_FLOATS * 4) {
    k_zero<<<1, 256, 0, stream>>>((float*)d_out);
    return;
  }

  float* ws = (float*)d_ws;
  int* flagp = (int*)d_ws;
  float* cva = ws + CV;
  float* XZm = cva + O_XZM;
  float* XZu = cva + O_XZU;
  float* XZg = cva + O_XZG;
  float* XZa = cva + O_XZA;
  float* aggr = cva + O_AGGR;
  float* aggB = cva + O_AGGB;
  float* upd = cva + O_UPD;
  float* msg = XZm;  // overlay (delayed-store ordering; see k_chain comment)

  k_detect<<<1, 64, 0, stream>>>((const u32*)nodes, flagp);
  k_convert<<<(CONV_TOTAL + 255) / 256, 256, 0, stream>>>(
      nodes, gattr,
      d_in[7], d_in[8], d_in[9], d_in[10],
      d_in[11], d_in[12], d_in[13], d_in[14],
      d_in[15], d_in[16], d_in[17], d_in[18],
      d_in[19], d_in[20], d_in[21], d_in[22],
      flagp, cva);
  k_pre<<<NEDGE + NNODE + BG, 256, 0, stream>>>(cva, eidx, nn, ne, XZm, XZu, XZg);
  k_chain<NEDGE><<<1, 512, 0, stream>>>(cva + O_WHM, XZm, msg);
  k_aggmin<<<NNODE, 128, 0, stream>>>(msg, eidx, aggr);
  k_aggproj<<<NNODE, 256, 0, stream>>>(cva, aggr, XZu);
  k_chain<NNODE><<<1, 512, 0, stream>>>(cva + O_WHU, XZu, upd);
  k_aggbmin<<<BG, 128, 0, stream>>>(upd, bidx, aggB);
  k_gproj<<<2 * BG, 256, 0, stream>>>(cva, aggB, upd, bidx, who, XZg, XZa);
  k_final<<<1, 256, 0, stream>>>(cva, XZg, XZa, (float*)d_out);
}